// Round 9
// baseline (209.295 us; speedup 1.0000x reference)
//
#include <hip/hip_runtime.h>

// VectorQuantizer (VQ-VAE quantize) for MI355X — R8: R7 structure with
// UNCAPPED registers (R7's launch_bounds(256,3) forced VGPR=84 < the ~112
// persistent live regs -> scratch spills on the dependent top-2 chain ->
// 124.9us latency-bound; R6 measured 49.8us).  Also: hierarchical loss
// accumulator (64 slots) to kill same-address f64 atomic serialization.
// d_in[0] = x [65536 x 64] f32, d_in[1] = embedding [512 x 64] f32
// d_out   = [loss(1) | quantized(4194304) | indices-as-float(65536)] f32
//
// np ref computes d in FLOAT32: d = A - (2x)@e.T + C. R3/R5 verified the
// bit-exact emulation; R6/R7 verified the MFMA-filter + margin + rescore:
//   d~ = C - 2*(xh.eh + xl.eh + xh.el)   (bf16 hi/lo split; A row-const)
//   |d~ - (np_d - A)| < ~3.2e-5  =>  MARGIN = 1e-4 (3x headroom).
// gap(d2-d1) > MARGIN  -> d~-argmin == np-argmin.
// gap <= MARGIN        -> exact np-fp32 full rescan of that row (~3%),
//                         distributed over 256 threads, lexicographic (d,k)
//                         min via packed u64 => np first-min semantics.

#define N_ROWS 65536
#define K_CODES 512
#define DIM 64
#define MARGIN 1e-4f

typedef short short8 __attribute__((ext_vector_type(8)));
typedef float f32x4 __attribute__((ext_vector_type(4)));

__device__ __forceinline__ unsigned short bf16_rne(float f) {
    unsigned u = __builtin_bit_cast(unsigned, f);
    u += 0x7FFFu + ((u >> 16) & 1u);
    return (unsigned short)(u >> 16);
}
__device__ __forceinline__ float bf16_f32(unsigned short h) {
    unsigned u = (unsigned)h << 16;
    return __builtin_bit_cast(float, u);
}
// order-preserving uint map of float (total order == IEEE < on finite values)
__device__ __forceinline__ unsigned ordu(float d) {
    unsigned b = __builtin_bit_cast(unsigned, d);
    return (b & 0x80000000u) ? ~b : (b | 0x80000000u);
}

// numpy fp32 pairwise sum of a[j]^2, n=64 (AVX512 path) — verified R3/R5.
__device__ __forceinline__ float np_sumsq64(const float* a) {
#pragma clang fp contract(off)
    float lane[16];
#pragma unroll
    for (int j = 0; j < 16; ++j) {
        float p0 = __fmul_rn(a[j],      a[j]);
        float p1 = __fmul_rn(a[j + 16], a[j + 16]);
        float p2 = __fmul_rn(a[j + 32], a[j + 32]);
        float p3 = __fmul_rn(a[j + 48], a[j + 48]);
        lane[j] = __fadd_rn(__fadd_rn(p0, p1), __fadd_rn(p2, p3));
    }
    float u[8];
#pragma unroll
    for (int j = 0; j < 8; ++j) u[j] = __fadd_rn(lane[j], lane[j + 8]);
    float v[4];
#pragma unroll
    for (int j = 0; j < 4; ++j) v[j] = __fadd_rn(u[j], u[j + 4]);
    return __fadd_rn(__fadd_rn(v[0], v[2]), __fadd_rn(v[1], v[3]));
}

// fragment-order index for B tables: code c, element j -> short index such
// that a wave's (g16,c16) lanes load 16B each, fully coalesced (1KB/instr).
__device__ __forceinline__ int frag_idx(int c, int j) {
    int blk = c >> 4, c16 = c & 15;
    int s = j >> 5, g16 = (j >> 3) & 3, e8 = j & 7;
    return ((((blk * 2 + s) * 4 + g16) * 16) + c16) * 8 + e8;
}

// prep: bf16 hi/lo split tables (fragment order) + np |e|^2 + zero acc/counter
__global__ __launch_bounds__(256) void vq_prep(
    const float* __restrict__ emb, unsigned short* __restrict__ ehT,
    unsigned short* __restrict__ elT, float* __restrict__ snp,
    double* __restrict__ acc, unsigned* __restrict__ counter)
{
    const int g = blockIdx.x * 256 + threadIdx.x;   // element id
    const int c = g >> 6, j = g & 63;
    float v = emb[c * DIM + j];
    unsigned short h = bf16_rne(v);
    int fi = frag_idx(c, j);
    ehT[fi] = h;
    elT[fi] = bf16_rne(__fsub_rn(v, bf16_f32(h)));
    if (blockIdx.x == 0) {
        for (int cc = threadIdx.x; cc < K_CODES; cc += 256) {
            float ev[DIM];
            const float4* e4 = reinterpret_cast<const float4*>(emb + cc * DIM);
#pragma unroll
            for (int t = 0; t < 16; ++t) {
                float4 w = e4[t];
                ev[4*t+0] = w.x; ev[4*t+1] = w.y; ev[4*t+2] = w.z; ev[4*t+3] = w.w;
            }
            snp[cc] = np_sumsq64(ev);
        }
        if (threadIdx.x < 64) acc[threadIdx.x] = 0.0;
        if (threadIdx.x == 64) counter[0] = 0u;
    }
}

__global__ __launch_bounds__(256, 2) void vq_main(
    const float* __restrict__ x, const float* __restrict__ emb,
    const unsigned short* __restrict__ ehT, const unsigned short* __restrict__ elT,
    const float* __restrict__ snp, float* __restrict__ out_q /* d_out+1 */,
    float* __restrict__ idx_out, double* __restrict__ acc,
    unsigned* __restrict__ counter, float* __restrict__ out0)
{
#pragma clang fp contract(off)
    __shared__ float rmd1[4][64], rmd2[4][64];
    __shared__ int   rmk1[4][64];
    __shared__ int   kfin[64];
    __shared__ int   needy[64];
    __shared__ int   nneedy;
    __shared__ unsigned long long smin64[64];
    __shared__ double bs[4];
    __shared__ int lastflag;

    const int tid = threadIdx.x;
    const int w = tid >> 6, l = tid & 63;
    const int g16 = l >> 4, c16 = l & 15;
    const size_t rowbase = (size_t)blockIdx.x * 64;

    if (tid == 0) nneedy = 0;
    if (tid < 64) smin64[tid] = ~0ull;

    // A-fragments straight from global x with on-the-fly bf16 hi/lo split.
    // lane (g16,c16) supplies x[rt*16 + c16][s*32 + g16*8 .. +7]  (R6-verified)
    short8 ah[4][2], al[4][2];
#pragma unroll
    for (int rt = 0; rt < 4; ++rt)
#pragma unroll
        for (int s = 0; s < 2; ++s) {
            const float4* p = reinterpret_cast<const float4*>(
                x + (rowbase + rt * 16 + c16) * DIM + s * 32 + g16 * 8);
            float4 v0 = p[0], v1 = p[1];
            float vv[8] = {v0.x, v0.y, v0.z, v0.w, v1.x, v1.y, v1.z, v1.w};
            short8 hh, ll;
#pragma unroll
            for (int e = 0; e < 8; ++e) {
                unsigned short h = bf16_rne(vv[e]);
                hh[e] = (short)h;
                ll[e] = (short)bf16_rne(__fsub_rn(vv[e], bf16_f32(h)));
            }
            ah[rt][s] = hh; al[rt][s] = ll;
        }

    // streaming MFMA scan: wave w covers code-tiles w*8 .. w*8+7
    float d1[16], d2[16];
    int k1[16];
#pragma unroll
    for (int s = 0; s < 16; ++s) { d1[s] = 1e30f; d2[s] = 1e30f; k1[s] = 0; }

#pragma unroll
    for (int ct = 0; ct < 8; ++ct) {
        const int tblk = w * 8 + ct;
        const int bbase = (tblk * 2) * 64 + l;      // x8 shorts, coalesced
        short8 bh0 = *reinterpret_cast<const short8*>(ehT + (size_t)bbase * 8);
        short8 bh1 = *reinterpret_cast<const short8*>(ehT + ((size_t)bbase + 64) * 8);
        short8 bl0 = *reinterpret_cast<const short8*>(elT + (size_t)bbase * 8);
        short8 bl1 = *reinterpret_cast<const short8*>(elT + ((size_t)bbase + 64) * 8);
        const int k = tblk * 16 + c16;
        const float snk = snp[k];
#pragma unroll
        for (int rt = 0; rt < 4; ++rt) {
            f32x4 a = {0.f, 0.f, 0.f, 0.f};
            a = __builtin_amdgcn_mfma_f32_16x16x32_bf16(ah[rt][0], bh0, a, 0, 0, 0);
            a = __builtin_amdgcn_mfma_f32_16x16x32_bf16(al[rt][0], bh0, a, 0, 0, 0);
            a = __builtin_amdgcn_mfma_f32_16x16x32_bf16(ah[rt][0], bl0, a, 0, 0, 0);
            a = __builtin_amdgcn_mfma_f32_16x16x32_bf16(ah[rt][1], bh1, a, 0, 0, 0);
            a = __builtin_amdgcn_mfma_f32_16x16x32_bf16(al[rt][1], bh1, a, 0, 0, 0);
            a = __builtin_amdgcn_mfma_f32_16x16x32_bf16(ah[rt][1], bl1, a, 0, 0, 0);
#pragma unroll
            for (int r = 0; r < 4; ++r) {
                float d = __fmaf_rn(-2.f, a[r], snk);   // C - 2M~
                const int sl = rt * 4 + r;
                // within a lane k ascends with ct -> strict < == first-min
                if (d < d1[sl]) { d2[sl] = d1[sl]; d1[sl] = d; k1[sl] = k; }
                else if (d < d2[sl]) { d2[sl] = d; }
            }
        }
    }

    // reduce over the 16 c16 lanes (codes) per row-slot: lex (d,k) + track d2
#pragma unroll
    for (int mask = 1; mask < 16; mask <<= 1) {
#pragma unroll
        for (int sl = 0; sl < 16; ++sl) {
            float od1 = __shfl_xor(d1[sl], mask, 64);
            int   ok1 = __shfl_xor(k1[sl], mask, 64);
            float od2 = __shfl_xor(d2[sl], mask, 64);
            float loser = fmaxf(d1[sl], od1);
            d2[sl] = fminf(fminf(d2[sl], od2), loser);
            if (od1 < d1[sl] || (od1 == d1[sl] && ok1 < k1[sl])) {
                d1[sl] = od1; k1[sl] = ok1;
            }
        }
    }
    if (c16 == 0) {
#pragma unroll
        for (int sl = 0; sl < 16; ++sl) {
            int row = (sl >> 2) * 16 + g16 * 4 + (sl & 3);
            rmd1[w][row] = d1[sl]; rmd2[w][row] = d2[sl]; rmk1[w][row] = k1[sl];
        }
    }
    __syncthreads();

    // cross-wave merge (4 partials per row) + needy detection
    if (tid < 64) {
        float bd1 = rmd1[0][tid], bd2 = rmd2[0][tid];
        int bk1 = rmk1[0][tid];
#pragma unroll
        for (int q = 1; q < 4; ++q) {
            float od1 = rmd1[q][tid], od2 = rmd2[q][tid];
            int ok1 = rmk1[q][tid];
            float loser = fmaxf(bd1, od1);
            bd2 = fminf(fminf(bd2, od2), loser);
            if (od1 < bd1 || (od1 == bd1 && ok1 < bk1)) { bd1 = od1; bk1 = ok1; }
        }
        kfin[tid] = bk1;
        if (bd2 - bd1 <= MARGIN) {            // near-tie: needs exact rescore
            int pos = atomicAdd(&nneedy, 1);
            needy[pos] = tid;
        }
    }
    __syncthreads();

    // distributed exact np-fp32 rescan (rare): 256 threads x 2 codes each
    const int nn = nneedy;
    for (int i = 0; i < nn; ++i) {
        const int row = needy[i];
        float xv[DIM];
        const float4* xr = reinterpret_cast<const float4*>(x + (rowbase + row) * DIM);
#pragma unroll
        for (int j = 0; j < 16; ++j) {
            float4 v = xr[j];
            xv[4*j+0] = v.x; xv[4*j+1] = v.y; xv[4*j+2] = v.z; xv[4*j+3] = v.w;
        }
        const float A = np_sumsq64(xv);
        const int ka = 2 * tid, kb = 2 * tid + 1;
        const float* ea = emb + ka * DIM;
        const float* eb = emb + kb * DIM;
        float ma = 0.f, mb = 0.f;      // sequential k-ordered sgemm chains
#pragma unroll
        for (int j = 0; j < DIM; ++j) {
            ma = __fmaf_rn(xv[j], ea[j], ma);
            mb = __fmaf_rn(xv[j], eb[j], mb);
        }
        float da = __fadd_rn(__fsub_rn(A, __fmul_rn(2.0f, ma)), snp[ka]);
        float db = __fadd_rn(__fsub_rn(A, __fmul_rn(2.0f, mb)), snp[kb]);
        // lexicographic (d, k): ka < kb
        unsigned long long pa = ((unsigned long long)ordu(da) << 16) | (unsigned)ka;
        unsigned long long pb = ((unsigned long long)ordu(db) << 16) | (unsigned)kb;
        atomicMin(&smin64[i], pa < pb ? pa : pb);
    }
    __syncthreads();
    if (tid < nn) kfin[needy[tid]] = (int)(smin64[tid] & 0xFFFFull);
    __syncthreads();

    if (tid < 64) idx_out[rowbase + tid] = (float)kfin[tid];

    // epilogue: quantized write + loss partial (emb rows are L2-hot, 128 KB)
    const size_t base = rowbase * DIM;
    float s = 0.f;
#pragma unroll
    for (int i = 0; i < 16; ++i) {
        int idx = i * 256 + tid;
        int r = idx >> 6, col = idx & 63;
        float qv = emb[kfin[r] * DIM + col];
        float xvv = x[base + idx];
        out_q[base + idx] = qv;
        float dq = __fsub_rn(qv, xvv);
        s = __fmaf_rn(dq, dq, s);
    }
    double sd = (double)s;
#pragma unroll
    for (int off = 32; off > 0; off >>= 1) sd += __shfl_down(sd, off, 64);
    if (l == 0) bs[w] = sd;
    __syncthreads();
    if (tid == 0) {
        // hierarchical: 64 accumulator slots kill same-address serialization
        atomicAdd(&acc[blockIdx.x & 63], (bs[0] + bs[1]) + (bs[2] + bs[3]));
        __threadfence();
        unsigned old = atomicAdd(counter, 1u);
        lastflag = (old == gridDim.x - 1) ? 1 : 0;
    }
    __syncthreads();
    if (lastflag && tid < 64) {
        double v = atomicAdd(&acc[tid], 0.0);   // device-scope coherent read
#pragma unroll
        for (int off = 32; off > 0; off >>= 1) v += __shfl_down(v, off, 64);
        if (tid == 0)
            out0[0] = (float)(1.25 * v / (double)((size_t)N_ROWS * DIM));
    }
}

extern "C" void kernel_launch(void* const* d_in, const int* in_sizes, int n_in,
                              void* d_out, int out_size, void* d_ws, size_t ws_size,
                              hipStream_t stream)
{
    const float* x   = (const float*)d_in[0];
    const float* emb = (const float*)d_in[1];
    float* out = (float*)d_out;
    char* ws = (char*)d_ws;
    double* acc = (double*)ws;                                   // 64 x 8 B
    unsigned* counter = (unsigned*)(ws + 512);                   // 4 B
    unsigned short* ehT = (unsigned short*)(ws + 4096);          // 64 KB
    unsigned short* elT = (unsigned short*)(ws + 4096 + 65536);  // 64 KB
    float* snp = (float*)(ws + 4096 + 131072);                   // 2 KB

    float* out_q = out + 1;
    float* idx_f = out + 1 + (size_t)N_ROWS * DIM;

    vq_prep<<<K_CODES * DIM / 256, 256, 0, stream>>>(emb, ehT, elT, snp,
                                                     acc, counter);
    vq_main<<<N_ROWS / 64, 256, 0, stream>>>(x, emb, ehT, elT, snp,
                                             out_q, idx_f, acc, counter, out);
}

// Round 10
// 190.301 us; speedup vs baseline: 1.0998x; 1.0998x over previous
//
#include <hip/hip_runtime.h>

// VectorQuantizer (VQ-VAE quantize) for MI355X — R10: R6's bookkeeping-free
// MFMA scan (dv write-only; R6=49.8us vs R7/R9's in-loop top-2 =125/151us)
// + R7's verified low-overhead pieces:
//   direct-global A-frags, fragment-ordered B tables (30 bank conflicts),
//   lazy Anp (only in rescan), distributed exact rescan, L2-direct epilogue,
//   2 dispatches, hierarchical f64 loss accumulator.
// 32 rows/block (rt=2) -> dv=64 regs, ~150 VGPR under (256,2) cap, LDS ~2KB.
//
// Numerics (PASS-verified R3/R5/R6/R7/R9): np ref computes d in FLOAT32:
//   d = A - (2x)@e.T + C.
// MFMA filter: d~ = C - 2*(xh.eh + xl.eh + xh.el), |err| < ~3.2e-5,
// MARGIN=1e-4. Exactly 1 candidate within MARGIN of rowmin -> it IS the
// np-argmin. Else: exact np-fp32 full rescan (pairwise sumsq, sequential
// k-ordered FMA chain, fl(fl(A-2M)+C), lexicographic (d,k) first-min).

#define N_ROWS 65536
#define K_CODES 512
#define DIM 64
#define MARGIN 1e-4f
#define RPB 32            // rows per block

typedef short short8 __attribute__((ext_vector_type(8)));
typedef float f32x4 __attribute__((ext_vector_type(4)));

__device__ __forceinline__ unsigned short bf16_rne(float f) {
    unsigned u = __builtin_bit_cast(unsigned, f);
    u += 0x7FFFu + ((u >> 16) & 1u);
    return (unsigned short)(u >> 16);
}
__device__ __forceinline__ float bf16_f32(unsigned short h) {
    unsigned u = (unsigned)h << 16;
    return __builtin_bit_cast(float, u);
}
// order-preserving uint map of float (total order == IEEE < on finite values)
__device__ __forceinline__ unsigned ordu(float d) {
    unsigned b = __builtin_bit_cast(unsigned, d);
    return (b & 0x80000000u) ? ~b : (b | 0x80000000u);
}

// numpy fp32 pairwise sum of a[j]^2, n=64 (AVX512 path) — verified R3/R5.
__device__ __forceinline__ float np_sumsq64(const float* a) {
#pragma clang fp contract(off)
    float lane[16];
#pragma unroll
    for (int j = 0; j < 16; ++j) {
        float p0 = __fmul_rn(a[j],      a[j]);
        float p1 = __fmul_rn(a[j + 16], a[j + 16]);
        float p2 = __fmul_rn(a[j + 32], a[j + 32]);
        float p3 = __fmul_rn(a[j + 48], a[j + 48]);
        lane[j] = __fadd_rn(__fadd_rn(p0, p1), __fadd_rn(p2, p3));
    }
    float u[8];
#pragma unroll
    for (int j = 0; j < 8; ++j) u[j] = __fadd_rn(lane[j], lane[j + 8]);
    float v[4];
#pragma unroll
    for (int j = 0; j < 4; ++j) v[j] = __fadd_rn(u[j], u[j + 4]);
    return __fadd_rn(__fadd_rn(v[0], v[2]), __fadd_rn(v[1], v[3]));
}

// fragment-order index for B tables (verified R7/R9): code c, element j.
__device__ __forceinline__ int frag_idx(int c, int j) {
    int blk = c >> 4, c16 = c & 15;
    int s = j >> 5, g16 = (j >> 3) & 3, e8 = j & 7;
    return ((((blk * 2 + s) * 4 + g16) * 16) + c16) * 8 + e8;
}

// prep: bf16 hi/lo split tables (fragment order) + np |e|^2 + zero acc/counter
__global__ __launch_bounds__(256) void vq_prep(
    const float* __restrict__ emb, unsigned short* __restrict__ ehT,
    unsigned short* __restrict__ elT, float* __restrict__ snp,
    double* __restrict__ acc, unsigned* __restrict__ counter)
{
    const int g = blockIdx.x * 256 + threadIdx.x;   // element id
    const int c = g >> 6, j = g & 63;
    float v = emb[c * DIM + j];
    unsigned short h = bf16_rne(v);
    int fi = frag_idx(c, j);
    ehT[fi] = h;
    elT[fi] = bf16_rne(__fsub_rn(v, bf16_f32(h)));
    if (blockIdx.x == 0) {
        for (int cc = threadIdx.x; cc < K_CODES; cc += 256) {
            float ev[DIM];
            const float4* e4 = reinterpret_cast<const float4*>(emb + cc * DIM);
#pragma unroll
            for (int t = 0; t < 16; ++t) {
                float4 w = e4[t];
                ev[4*t+0] = w.x; ev[4*t+1] = w.y; ev[4*t+2] = w.z; ev[4*t+3] = w.w;
            }
            snp[cc] = np_sumsq64(ev);
        }
        if (threadIdx.x < 64) acc[threadIdx.x] = 0.0;
        if (threadIdx.x == 64) counter[0] = 0u;
    }
}

__global__ __launch_bounds__(256, 2) void vq_main(
    const float* __restrict__ x, const float* __restrict__ emb,
    const unsigned short* __restrict__ ehT, const unsigned short* __restrict__ elT,
    const float* __restrict__ snp, float* __restrict__ out_q /* d_out+1 */,
    float* __restrict__ idx_out, double* __restrict__ acc,
    unsigned* __restrict__ counter, float* __restrict__ out0)
{
#pragma clang fp contract(off)
    __shared__ float rmw[4][RPB];       // per-wave row minima
    __shared__ float rowmin_s[RPB];
    __shared__ int   ccnt[RPB];
    __shared__ int   ck[RPB][8];        // candidate lists (cap 8; >=2 -> rescan)
    __shared__ int   kfin[RPB];
    __shared__ int   needy[RPB];
    __shared__ int   nneedy;
    __shared__ unsigned long long smin64[RPB];
    __shared__ double bs[4];
    __shared__ int lastflag;

    const int tid = threadIdx.x;
    const int w = tid >> 6, l = tid & 63;
    const int g16 = l >> 4, c16 = l & 15;
    const size_t rowbase = (size_t)blockIdx.x * RPB;

    if (tid == 0) nneedy = 0;
    if (tid < RPB) { ccnt[tid] = 0; smin64[tid] = ~0ull; }
    __syncthreads();

    // A-frags direct from global with on-the-fly bf16 split (verified R7):
    // lane (g16,c16) supplies x[rt*16 + c16][s*32 + g16*8 .. +7]
    short8 ah[2][2], al[2][2];
#pragma unroll
    for (int rt = 0; rt < 2; ++rt)
#pragma unroll
        for (int s = 0; s < 2; ++s) {
            const float4* p = reinterpret_cast<const float4*>(
                x + (rowbase + rt * 16 + c16) * DIM + s * 32 + g16 * 8);
            float4 v0 = p[0], v1 = p[1];
            float vv[8] = {v0.x, v0.y, v0.z, v0.w, v1.x, v1.y, v1.z, v1.w};
            short8 hh, ll;
#pragma unroll
            for (int e = 0; e < 8; ++e) {
                unsigned short h = bf16_rne(vv[e]);
                hh[e] = (short)h;
                ll[e] = (short)bf16_rne(__fsub_rn(vv[e], bf16_f32(h)));
            }
            ah[rt][s] = hh; al[rt][s] = ll;
        }

    // MFMA scan, ZERO per-element bookkeeping (R6 structure): dv write-only.
    float dv[2][8][4];
#pragma unroll
    for (int ct = 0; ct < 8; ++ct) {
        const int tblk = w * 8 + ct;
        const int bbase = (tblk * 2) * 64 + l;      // x8 shorts, coalesced
        short8 bh0 = *reinterpret_cast<const short8*>(ehT + (size_t)bbase * 8);
        short8 bh1 = *reinterpret_cast<const short8*>(ehT + ((size_t)bbase + 64) * 8);
        short8 bl0 = *reinterpret_cast<const short8*>(elT + (size_t)bbase * 8);
        short8 bl1 = *reinterpret_cast<const short8*>(elT + ((size_t)bbase + 64) * 8);
        const float snk = snp[tblk * 16 + c16];
#pragma unroll
        for (int rt = 0; rt < 2; ++rt) {
            f32x4 a = {0.f, 0.f, 0.f, 0.f};
            a = __builtin_amdgcn_mfma_f32_16x16x32_bf16(ah[rt][0], bh0, a, 0, 0, 0);
            a = __builtin_amdgcn_mfma_f32_16x16x32_bf16(al[rt][0], bh0, a, 0, 0, 0);
            a = __builtin_amdgcn_mfma_f32_16x16x32_bf16(ah[rt][0], bl0, a, 0, 0, 0);
            a = __builtin_amdgcn_mfma_f32_16x16x32_bf16(ah[rt][1], bh1, a, 0, 0, 0);
            a = __builtin_amdgcn_mfma_f32_16x16x32_bf16(al[rt][1], bh1, a, 0, 0, 0);
            a = __builtin_amdgcn_mfma_f32_16x16x32_bf16(ah[rt][1], bl1, a, 0, 0, 0);
#pragma unroll
            for (int r = 0; r < 4; ++r)
                dv[rt][ct][r] = __fmaf_rn(-2.f, a[r], snk);   // C - 2M~
        }
    }

    // row minima: independent fminf tree (no k tracking), then 16-lane shuffle
    float lmin[8];
#pragma unroll
    for (int rt = 0; rt < 2; ++rt)
#pragma unroll
        for (int r = 0; r < 4; ++r) {
            float m = dv[rt][0][r];
#pragma unroll
            for (int ct = 1; ct < 8; ++ct) m = fminf(m, dv[rt][ct][r]);
            lmin[rt * 4 + r] = m;
        }
#pragma unroll
    for (int mask = 1; mask < 16; mask <<= 1)
#pragma unroll
        for (int sl = 0; sl < 8; ++sl)
            lmin[sl] = fminf(lmin[sl], __shfl_xor(lmin[sl], mask, 64));
    if (c16 == 0)
#pragma unroll
        for (int sl = 0; sl < 8; ++sl)
            rmw[w][(sl >> 2) * 16 + g16 * 4 + (sl & 3)] = lmin[sl];
    __syncthreads();
    if (tid < RPB)
        rowmin_s[tid] = fminf(fminf(rmw[0][tid], rmw[1][tid]),
                              fminf(rmw[2][tid], rmw[3][tid]));
    __syncthreads();

    // candidate append (predicated, rare hits ~1/row)
#pragma unroll
    for (int rt = 0; rt < 2; ++rt)
#pragma unroll
        for (int ct = 0; ct < 8; ++ct)
#pragma unroll
            for (int r = 0; r < 4; ++r) {
                const int row = rt * 16 + g16 * 4 + r;
                if (dv[rt][ct][r] <= rowmin_s[row] + MARGIN) {
                    int pos = atomicAdd(&ccnt[row], 1);
                    if (pos < 8) ck[row][pos] = w * 128 + ct * 16 + c16;
                }
            }
    __syncthreads();

    // unique candidate -> done; else needy (exact rescan over ALL codes)
    if (tid < RPB) {
        if (ccnt[tid] == 1) kfin[tid] = ck[tid][0];
        else { int pos = atomicAdd(&nneedy, 1); needy[pos] = tid; }
    }
    __syncthreads();

    // distributed exact np-fp32 rescan (verified R7): 256 threads x 2 codes
    const int nn = nneedy;
    for (int i = 0; i < nn; ++i) {
        const int row = needy[i];
        float xv[DIM];
        const float4* xr = reinterpret_cast<const float4*>(x + (rowbase + row) * DIM);
#pragma unroll
        for (int j = 0; j < 16; ++j) {
            float4 v = xr[j];
            xv[4*j+0] = v.x; xv[4*j+1] = v.y; xv[4*j+2] = v.z; xv[4*j+3] = v.w;
        }
        const float A = np_sumsq64(xv);     // lazy: only for needy rows
        const int ka = 2 * tid, kb = 2 * tid + 1;
        const float* ea = emb + ka * DIM;
        const float* eb = emb + kb * DIM;
        float ma = 0.f, mb = 0.f;           // sequential k-ordered sgemm chains
#pragma unroll
        for (int j = 0; j < DIM; ++j) {
            ma = __fmaf_rn(xv[j], ea[j], ma);
            mb = __fmaf_rn(xv[j], eb[j], mb);
        }
        float da = __fadd_rn(__fsub_rn(A, __fmul_rn(2.0f, ma)), snp[ka]);
        float db = __fadd_rn(__fsub_rn(A, __fmul_rn(2.0f, mb)), snp[kb]);
        unsigned long long pa = ((unsigned long long)ordu(da) << 16) | (unsigned)ka;
        unsigned long long pb = ((unsigned long long)ordu(db) << 16) | (unsigned)kb;
        atomicMin(&smin64[i], pa < pb ? pa : pb);
    }
    __syncthreads();
    if (tid < nn) kfin[needy[tid]] = (int)(smin64[tid] & 0xFFFFull);
    __syncthreads();

    if (tid < RPB) idx_out[rowbase + tid] = (float)kfin[tid];

    // epilogue: quantized write + loss partial (emb L2-hot, 128 KB)
    const size_t base = rowbase * DIM;
    float s = 0.f;
#pragma unroll
    for (int i = 0; i < RPB * DIM / 256; ++i) {
        int idx = i * 256 + tid;
        int r = idx >> 6, col = idx & 63;
        float qv = emb[kfin[r] * DIM + col];
        float xvv = x[base + idx];
        out_q[base + idx] = qv;
        float dq = __fsub_rn(qv, xvv);
        s = __fmaf_rn(dq, dq, s);
    }
    double sd = (double)s;
#pragma unroll
    for (int off = 32; off > 0; off >>= 1) sd += __shfl_down(sd, off, 64);
    if (l == 0) bs[w] = sd;
    __syncthreads();
    if (tid == 0) {
        atomicAdd(&acc[blockIdx.x & 63], (bs[0] + bs[1]) + (bs[2] + bs[3]));
        __threadfence();
        unsigned old = atomicAdd(counter, 1u);
        lastflag = (old == gridDim.x - 1) ? 1 : 0;
    }
    __syncthreads();
    if (lastflag && tid < 64) {
        double v = atomicAdd(&acc[tid], 0.0);   // device-scope coherent read
#pragma unroll
        for (int off = 32; off > 0; off >>= 1) v += __shfl_down(v, off, 64);
        if (tid == 0)
            out0[0] = (float)(1.25 * v / (double)((size_t)N_ROWS * DIM));
    }
}

extern "C" void kernel_launch(void* const* d_in, const int* in_sizes, int n_in,
                              void* d_out, int out_size, void* d_ws, size_t ws_size,
                              hipStream_t stream)
{
    const float* x   = (const float*)d_in[0];
    const float* emb = (const float*)d_in[1];
    float* out = (float*)d_out;
    char* ws = (char*)d_ws;
    double* acc = (double*)ws;                                   // 64 x 8 B
    unsigned* counter = (unsigned*)(ws + 512);                   // 4 B
    unsigned short* ehT = (unsigned short*)(ws + 4096);          // 64 KB
    unsigned short* elT = (unsigned short*)(ws + 4096 + 65536);  // 64 KB
    float* snp = (float*)(ws + 4096 + 131072);                   // 2 KB

    float* out_q = out + 1;
    float* idx_f = out + 1 + (size_t)N_ROWS * DIM;

    vq_prep<<<K_CODES * DIM / 256, 256, 0, stream>>>(emb, ehT, elT, snp,
                                                     acc, counter);
    vq_main<<<N_ROWS / RPB, 256, 0, stream>>>(x, emb, ehT, elT, snp,
                                              out_q, idx_f, acc, counter, out);
}

// Round 13
// 150.684 us; speedup vs baseline: 1.3890x; 1.2629x over previous
//
#include <hip/hip_runtime.h>

// VectorQuantizer (VQ-VAE quantize) for MI355X — R11: R10 minus the in-kernel
// device fence.  R7/R9/R10 all carried __threadfence()+counter+lastflag and
// all landed 125-151us with >80% no-issue cycles; R6 (separate finalize
// kernel, no fence) ran 49.8us.  On MI355X a device-scope release must push
// dirty L2 lines (16MB of out_q!) to the die-level coherence point per block
// (per-XCD L2s non-coherent) -> chip-wide stalls.  Kernel boundary does that
// release ONCE.  vq_main tail = plain hierarchical f64 atomicAdd only;
// finalize is a 3rd tiny dispatch (R6-verified visibility pattern).
//
// Numerics (PASS-verified R3/R5/R6/R7/R9/R10): np ref computes d in FLOAT32:
//   d = A - (2x)@e.T + C.
// MFMA filter: d~ = C - 2*(xh.eh + xl.eh + xh.el), |err| < ~3.2e-5,
// MARGIN=1e-4. Exactly 1 candidate within MARGIN of rowmin -> it IS the
// np-argmin. Else: exact np-fp32 full rescan (pairwise sumsq, sequential
// k-ordered FMA chain, fl(fl(A-2M)+C), lexicographic (d,k) first-min).

#define N_ROWS 65536
#define K_CODES 512
#define DIM 64
#define MARGIN 1e-4f
#define RPB 32            // rows per block

typedef short short8 __attribute__((ext_vector_type(8)));
typedef float f32x4 __attribute__((ext_vector_type(4)));

__device__ __forceinline__ unsigned short bf16_rne(float f) {
    unsigned u = __builtin_bit_cast(unsigned, f);
    u += 0x7FFFu + ((u >> 16) & 1u);
    return (unsigned short)(u >> 16);
}
__device__ __forceinline__ float bf16_f32(unsigned short h) {
    unsigned u = (unsigned)h << 16;
    return __builtin_bit_cast(float, u);
}
// order-preserving uint map of float (total order == IEEE < on finite values)
__device__ __forceinline__ unsigned ordu(float d) {
    unsigned b = __builtin_bit_cast(unsigned, d);
    return (b & 0x80000000u) ? ~b : (b | 0x80000000u);
}

// numpy fp32 pairwise sum of a[j]^2, n=64 (AVX512 path) — verified R3/R5.
__device__ __forceinline__ float np_sumsq64(const float* a) {
#pragma clang fp contract(off)
    float lane[16];
#pragma unroll
    for (int j = 0; j < 16; ++j) {
        float p0 = __fmul_rn(a[j],      a[j]);
        float p1 = __fmul_rn(a[j + 16], a[j + 16]);
        float p2 = __fmul_rn(a[j + 32], a[j + 32]);
        float p3 = __fmul_rn(a[j + 48], a[j + 48]);
        lane[j] = __fadd_rn(__fadd_rn(p0, p1), __fadd_rn(p2, p3));
    }
    float u[8];
#pragma unroll
    for (int j = 0; j < 8; ++j) u[j] = __fadd_rn(lane[j], lane[j + 8]);
    float v[4];
#pragma unroll
    for (int j = 0; j < 4; ++j) v[j] = __fadd_rn(u[j], u[j + 4]);
    return __fadd_rn(__fadd_rn(v[0], v[2]), __fadd_rn(v[1], v[3]));
}

// fragment-order index for B tables (verified R7/R9/R10): code c, element j.
__device__ __forceinline__ int frag_idx(int c, int j) {
    int blk = c >> 4, c16 = c & 15;
    int s = j >> 5, g16 = (j >> 3) & 3, e8 = j & 7;
    return ((((blk * 2 + s) * 4 + g16) * 16) + c16) * 8 + e8;
}

// prep: bf16 hi/lo split tables (fragment order) + np |e|^2 + zero acc
__global__ __launch_bounds__(256) void vq_prep(
    const float* __restrict__ emb, unsigned short* __restrict__ ehT,
    unsigned short* __restrict__ elT, float* __restrict__ snp,
    double* __restrict__ acc)
{
    const int g = blockIdx.x * 256 + threadIdx.x;   // element id
    const int c = g >> 6, j = g & 63;
    float v = emb[c * DIM + j];
    unsigned short h = bf16_rne(v);
    int fi = frag_idx(c, j);
    ehT[fi] = h;
    elT[fi] = bf16_rne(__fsub_rn(v, bf16_f32(h)));
    if (blockIdx.x == 0) {
        for (int cc = threadIdx.x; cc < K_CODES; cc += 256) {
            float ev[DIM];
            const float4* e4 = reinterpret_cast<const float4*>(emb + cc * DIM);
#pragma unroll
            for (int t = 0; t < 16; ++t) {
                float4 w = e4[t];
                ev[4*t+0] = w.x; ev[4*t+1] = w.y; ev[4*t+2] = w.z; ev[4*t+3] = w.w;
            }
            snp[cc] = np_sumsq64(ev);
        }
        if (threadIdx.x < 64) acc[threadIdx.x] = 0.0;
    }
}

__global__ __launch_bounds__(256, 2) void vq_main(
    const float* __restrict__ x, const float* __restrict__ emb,
    const unsigned short* __restrict__ ehT, const unsigned short* __restrict__ elT,
    const float* __restrict__ snp, float* __restrict__ out_q /* d_out+1 */,
    float* __restrict__ idx_out, double* __restrict__ acc)
{
#pragma clang fp contract(off)
    __shared__ float rmw[4][RPB];       // per-wave row minima
    __shared__ float rowmin_s[RPB];
    __shared__ int   ccnt[RPB];
    __shared__ int   ck[RPB][8];        // candidate lists (cap 8; >=2 -> rescan)
    __shared__ int   kfin[RPB];
    __shared__ int   needy[RPB];
    __shared__ int   nneedy;
    __shared__ unsigned long long smin64[RPB];
    __shared__ double bs[4];

    const int tid = threadIdx.x;
    const int w = tid >> 6, l = tid & 63;
    const int g16 = l >> 4, c16 = l & 15;
    const size_t rowbase = (size_t)blockIdx.x * RPB;

    if (tid == 0) nneedy = 0;
    if (tid < RPB) { ccnt[tid] = 0; smin64[tid] = ~0ull; }
    __syncthreads();

    // A-frags direct from global with on-the-fly bf16 split (verified R7):
    // lane (g16,c16) supplies x[rt*16 + c16][s*32 + g16*8 .. +7]
    short8 ah[2][2], al[2][2];
#pragma unroll
    for (int rt = 0; rt < 2; ++rt)
#pragma unroll
        for (int s = 0; s < 2; ++s) {
            const float4* p = reinterpret_cast<const float4*>(
                x + (rowbase + rt * 16 + c16) * DIM + s * 32 + g16 * 8);
            float4 v0 = p[0], v1 = p[1];
            float vv[8] = {v0.x, v0.y, v0.z, v0.w, v1.x, v1.y, v1.z, v1.w};
            short8 hh, ll;
#pragma unroll
            for (int e = 0; e < 8; ++e) {
                unsigned short h = bf16_rne(vv[e]);
                hh[e] = (short)h;
                ll[e] = (short)bf16_rne(__fsub_rn(vv[e], bf16_f32(h)));
            }
            ah[rt][s] = hh; al[rt][s] = ll;
        }

    // MFMA scan, ZERO per-element bookkeeping (R6 structure): dv write-only.
    float dv[2][8][4];
#pragma unroll
    for (int ct = 0; ct < 8; ++ct) {
        const int tblk = w * 8 + ct;
        const int bbase = (tblk * 2) * 64 + l;      // x8 shorts, coalesced
        short8 bh0 = *reinterpret_cast<const short8*>(ehT + (size_t)bbase * 8);
        short8 bh1 = *reinterpret_cast<const short8*>(ehT + ((size_t)bbase + 64) * 8);
        short8 bl0 = *reinterpret_cast<const short8*>(elT + (size_t)bbase * 8);
        short8 bl1 = *reinterpret_cast<const short8*>(elT + ((size_t)bbase + 64) * 8);
        const float snk = snp[tblk * 16 + c16];
#pragma unroll
        for (int rt = 0; rt < 2; ++rt) {
            f32x4 a = {0.f, 0.f, 0.f, 0.f};
            a = __builtin_amdgcn_mfma_f32_16x16x32_bf16(ah[rt][0], bh0, a, 0, 0, 0);
            a = __builtin_amdgcn_mfma_f32_16x16x32_bf16(al[rt][0], bh0, a, 0, 0, 0);
            a = __builtin_amdgcn_mfma_f32_16x16x32_bf16(ah[rt][0], bl0, a, 0, 0, 0);
            a = __builtin_amdgcn_mfma_f32_16x16x32_bf16(ah[rt][1], bh1, a, 0, 0, 0);
            a = __builtin_amdgcn_mfma_f32_16x16x32_bf16(al[rt][1], bh1, a, 0, 0, 0);
            a = __builtin_amdgcn_mfma_f32_16x16x32_bf16(ah[rt][1], bl1, a, 0, 0, 0);
#pragma unroll
            for (int r = 0; r < 4; ++r)
                dv[rt][ct][r] = __fmaf_rn(-2.f, a[r], snk);   // C - 2M~
        }
    }

    // row minima: independent fminf tree (no k tracking), then 16-lane shuffle
    float lmin[8];
#pragma unroll
    for (int rt = 0; rt < 2; ++rt)
#pragma unroll
        for (int r = 0; r < 4; ++r) {
            float m = dv[rt][0][r];
#pragma unroll
            for (int ct = 1; ct < 8; ++ct) m = fminf(m, dv[rt][ct][r]);
            lmin[rt * 4 + r] = m;
        }
#pragma unroll
    for (int mask = 1; mask < 16; mask <<= 1)
#pragma unroll
        for (int sl = 0; sl < 8; ++sl)
            lmin[sl] = fminf(lmin[sl], __shfl_xor(lmin[sl], mask, 64));
    if (c16 == 0)
#pragma unroll
        for (int sl = 0; sl < 8; ++sl)
            rmw[w][(sl >> 2) * 16 + g16 * 4 + (sl & 3)] = lmin[sl];
    __syncthreads();
    if (tid < RPB)
        rowmin_s[tid] = fminf(fminf(rmw[0][tid], rmw[1][tid]),
                              fminf(rmw[2][tid], rmw[3][tid]));
    __syncthreads();

    // candidate append (predicated, rare hits ~1/row)
#pragma unroll
    for (int rt = 0; rt < 2; ++rt)
#pragma unroll
        for (int ct = 0; ct < 8; ++ct)
#pragma unroll
            for (int r = 0; r < 4; ++r) {
                const int row = rt * 16 + g16 * 4 + r;
                if (dv[rt][ct][r] <= rowmin_s[row] + MARGIN) {
                    int pos = atomicAdd(&ccnt[row], 1);
                    if (pos < 8) ck[row][pos] = w * 128 + ct * 16 + c16;
                }
            }
    __syncthreads();

    // unique candidate -> done; else needy (exact rescan over ALL codes)
    if (tid < RPB) {
        if (ccnt[tid] == 1) kfin[tid] = ck[tid][0];
        else { int pos = atomicAdd(&nneedy, 1); needy[pos] = tid; }
    }
    __syncthreads();

    // distributed exact np-fp32 rescan (verified R7): 256 threads x 2 codes
    const int nn = nneedy;
    for (int i = 0; i < nn; ++i) {
        const int row = needy[i];
        float xv[DIM];
        const float4* xr = reinterpret_cast<const float4*>(x + (rowbase + row) * DIM);
#pragma unroll
        for (int j = 0; j < 16; ++j) {
            float4 v = xr[j];
            xv[4*j+0] = v.x; xv[4*j+1] = v.y; xv[4*j+2] = v.z; xv[4*j+3] = v.w;
        }
        const float A = np_sumsq64(xv);     // lazy: only for needy rows
        const int ka = 2 * tid, kb = 2 * tid + 1;
        const float* ea = emb + ka * DIM;
        const float* eb = emb + kb * DIM;
        float ma = 0.f, mb = 0.f;           // sequential k-ordered sgemm chains
#pragma unroll
        for (int j = 0; j < DIM; ++j) {
            ma = __fmaf_rn(xv[j], ea[j], ma);
            mb = __fmaf_rn(xv[j], eb[j], mb);
        }
        float da = __fadd_rn(__fsub_rn(A, __fmul_rn(2.0f, ma)), snp[ka]);
        float db = __fadd_rn(__fsub_rn(A, __fmul_rn(2.0f, mb)), snp[kb]);
        unsigned long long pa = ((unsigned long long)ordu(da) << 16) | (unsigned)ka;
        unsigned long long pb = ((unsigned long long)ordu(db) << 16) | (unsigned)kb;
        atomicMin(&smin64[i], pa < pb ? pa : pb);
    }
    __syncthreads();
    if (tid < nn) kfin[needy[tid]] = (int)(smin64[tid] & 0xFFFFull);
    __syncthreads();

    if (tid < RPB) idx_out[rowbase + tid] = (float)kfin[tid];

    // epilogue: quantized write + loss partial (emb L2-hot, 128 KB)
    const size_t base = rowbase * DIM;
    float s = 0.f;
#pragma unroll
    for (int i = 0; i < RPB * DIM / 256; ++i) {
        int idx = i * 256 + tid;
        int r = idx >> 6, col = idx & 63;
        float qv = emb[kfin[r] * DIM + col];
        float xvv = x[base + idx];
        out_q[base + idx] = qv;
        float dq = __fsub_rn(qv, xvv);
        s = __fmaf_rn(dq, dq, s);
    }
    double sd = (double)s;
#pragma unroll
    for (int off = 32; off > 0; off >>= 1) sd += __shfl_down(sd, off, 64);
    if (l == 0) bs[w] = sd;
    __syncthreads();
    // NO __threadfence / counter / lastflag here (R10's 100us stall source):
    // fire-and-forget hierarchical f64 atomic; visibility to the finalize
    // kernel comes from the dispatch-boundary release (R6-verified pattern).
    if (tid == 0)
        atomicAdd(&acc[blockIdx.x & 63], (bs[0] + bs[1]) + (bs[2] + bs[3]));
}

// 3rd dispatch: reduce the 64 partial sums -> loss (kernel boundary = fence)
__global__ void vq_finalize(const double* __restrict__ acc,
                            float* __restrict__ out0)
{
    const int t = threadIdx.x;           // 64 threads
    double v = acc[t];
#pragma unroll
    for (int off = 32; off > 0; off >>= 1) v += __shfl_down(v, off, 64);
    if (t == 0)
        out0[0] = (float)(1.25 * v / (double)((size_t)N_ROWS * DIM));
}

extern "C" void kernel_launch(void* const* d_in, const int* in_sizes, int n_in,
                              void* d_out, int out_size, void* d_ws, size_t ws_size,
                              hipStream_t stream)
{
    const float* x   = (const float*)d_in[0];
    const float* emb = (const float*)d_in[1];
    float* out = (float*)d_out;
    char* ws = (char*)d_ws;
    double* acc = (double*)ws;                                   // 64 x 8 B
    unsigned short* ehT = (unsigned short*)(ws + 4096);          // 64 KB
    unsigned short* elT = (unsigned short*)(ws + 4096 + 65536);  // 64 KB
    float* snp = (float*)(ws + 4096 + 131072);                   // 2 KB

    float* out_q = out + 1;
    float* idx_f = out + 1 + (size_t)N_ROWS * DIM;

    vq_prep<<<K_CODES * DIM / 256, 256, 0, stream>>>(emb, ehT, elT, snp, acc);
    vq_main<<<N_ROWS / RPB, 256, 0, stream>>>(x, emb, ehT, elT, snp,
                                              out_q, idx_f, acc);
    vq_finalize<<<1, 64, 0, stream>>>(acc, out);
}